// Round 4
// baseline (94.444 us; speedup 1.0000x reference)
//
#include <hip/hip_runtime.h>
#include <hip/hip_bf16.h>

// Quantum layer, 4 qubits, B=2^20.
// out_w(x) = sum_{t in {0,1,2}^4} C_w[t] * prod_q f_q(t_q),
//   f(0)=1, f(1)=cos x_q, f(2)=sin x_q   (81 coefficients x 4 outputs).
// C depends only on weights (36 floats).
//
// R4: the 76us bottleneck was build_C_kernel — one block, serial libm
// sincosf (Payne-Hanek call trees) on an idle GPU. Fix: (a) all trig via
// __sincosf (v_sin_f32/v_cos_f32 HW ops); (b) 12 gate matrices computed in
// parallel by 12 threads; (c) the whole C-construction is FUSED as a
// prologue into every qlayer block (redundant across 1024 co-resident
// blocks -> ~2us wall once, no second kernel, no launch dependency).

#define SPT 4
#define BLOCK 256

template <bool GUARD>
__launch_bounds__(BLOCK)
__global__ void qlayer_kernel(const float* __restrict__ x,
                              const float* __restrict__ w,
                              float* __restrict__ out, int B) {
    __shared__ float Gm[12][8];     // per-gate 2x2 complex matrix
    __shared__ float Vr[16][16];    // folded unitary, [row j][col k]
    __shared__ float Vi[16][16];
    __shared__ float A[4][16][16];  // quadratic forms per output wire
    __shared__ float4 C[81];        // final polynomial coefficients

    const int tid = threadIdx.x;

    // ---- Prologue phase 0: 12 threads compute the 12 Rot gate matrices ----
    if (tid < 12) {
        float phi = w[tid * 3 + 0];
        float th  = w[tid * 3 + 1];
        float om  = w[tid * 3 + 2];
        float ct, st, sa, ca, sb, cb;
        __sincosf(0.5f * th, &st, &ct);
        __sincosf(0.5f * (phi + om), &sa, &ca);
        __sincosf(0.5f * (phi - om), &sb, &cb);
        Gm[tid][0] =  ca * ct;  Gm[tid][1] = -sa * ct;   // m00
        Gm[tid][2] = -cb * st;  Gm[tid][3] = -sb * st;   // m01
        Gm[tid][4] =  cb * st;  Gm[tid][5] = -sb * st;   // m10
        Gm[tid][6] =  ca * ct;  Gm[tid][7] =  sa * ct;   // m11
    }
    __syncthreads();

    // ---- Prologue phase 1: 16 threads build column k of the circuit ----
    if (tid < 16) {
        const int k = tid;
        float ar[16], ai[16];
#pragma unroll
        for (int j = 0; j < 16; ++j) { ar[j] = (j == k) ? 1.f : 0.f; ai[j] = 0.f; }

#pragma unroll
        for (int l = 0; l < 3; ++l) {
#pragma unroll
            for (int i = 0; i < 4; ++i) {
                const int g = l * 4 + i;
                float m00r = Gm[g][0], m00i = Gm[g][1];
                float m01r = Gm[g][2], m01i = Gm[g][3];
                float m10r = Gm[g][4], m10i = Gm[g][5];
                float m11r = Gm[g][6], m11i = Gm[g][7];
                int mask = 1 << i;
#pragma unroll
                for (int j = 0; j < 16; ++j) {
                    if (j & mask) continue;
                    int j1 = j | mask;
                    float a0r = ar[j],  a0i = ai[j];
                    float a1r = ar[j1], a1i = ai[j1];
                    ar[j]  = m00r * a0r - m00i * a0i + m01r * a1r - m01i * a1i;
                    ai[j]  = m00r * a0i + m00i * a0r + m01r * a1i + m01i * a1r;
                    ar[j1] = m10r * a0r - m10i * a0i + m11r * a1r - m11i * a1i;
                    ai[j1] = m10r * a0i + m10i * a0r + m11r * a1i + m11i * a1r;
                }
            }
            int r = (l % 3) + 1;
#pragma unroll
            for (int i = 0; i < 4; ++i) {
                int c = i, t = (i + r) & 3;
                int cm = 1 << c, tm = 1 << t;
#pragma unroll
                for (int j = 0; j < 16; ++j) {
                    if ((j & cm) && !(j & tm)) {
                        int j2 = j | tm;
                        float tr = ar[j], ti = ai[j];
                        ar[j] = ar[j2]; ai[j] = ai[j2];
                        ar[j2] = tr;    ai[j2] = ti;
                    }
                }
            }
        }

        // fold RX input phase (-i)^popcount(k)
        int p = __popc(k) & 3;
        float pr = (p == 0) ? 1.f : (p == 2) ? -1.f : 0.f;
        float pi = (p == 1) ? -1.f : (p == 3) ? 1.f : 0.f;
#pragma unroll
        for (int j = 0; j < 16; ++j) {
            Vr[j][k] = ar[j] * pr - ai[j] * pi;
            Vi[j][k] = ar[j] * pi + ai[j] * pr;
        }
    }
    __syncthreads();

    // ---- Prologue phase 2: A_w[k,l] (all 256 threads) ----
    {
        const int k = tid >> 4, l = tid & 15;
        float acc0 = 0.f, acc1 = 0.f, acc2 = 0.f, acc3 = 0.f;
#pragma unroll
        for (int j = 0; j < 16; ++j) {
            float p = Vr[j][k] * Vr[j][l] + Vi[j][k] * Vi[j][l];
            acc0 += (j & 1) ? -p : p;
            acc1 += (j & 2) ? -p : p;
            acc2 += (j & 4) ? -p : p;
            acc3 += (j & 8) ? -p : p;
        }
        A[0][k][l] = acc0; A[1][k][l] = acc1; A[2][k][l] = acc2; A[3][k][l] = acc3;
    }
    __syncthreads();

    // ---- Prologue phase 3: C_w[t] = (1/16) sum of 16 signed A entries ----
    if (tid < 81) {
        int d0 = tid % 3, d1 = (tid / 3) % 3, d2 = (tid / 9) % 3, d3 = tid / 27;
        int d[4] = {d0, d1, d2, d3};
        float acc0 = 0.f, acc1 = 0.f, acc2 = 0.f, acc3 = 0.f;
#pragma unroll
        for (int o = 0; o < 16; ++o) {
            int k = 0, l = 0; float sign = 1.f;
#pragma unroll
            for (int q = 0; q < 4; ++q) {
                int oq = (o >> q) & 1;
                if (d[q] == 2) { k |= oq << q; l |= (1 - oq) << q; }
                else {
                    k |= oq << q; l |= oq << q;
                    if (d[q] == 1 && oq == 1) sign = -sign;
                }
            }
            acc0 += sign * A[0][k][l];
            acc1 += sign * A[1][k][l];
            acc2 += sign * A[2][k][l];
            acc3 += sign * A[3][k][l];
        }
        const float inv16 = 0.0625f;
        C[tid] = make_float4(acc0 * inv16, acc1 * inv16, acc2 * inv16, acc3 * inv16);
    }
    __syncthreads();

    // ---- Main loop: polynomial evaluation, SPT samples per thread ----
    const int base = blockIdx.x * (BLOCK * SPT) + tid;

    float c0[SPT], s0[SPT], c3[SPT], s3[SPT];
    float G9[SPT][9];
    float z[SPT][4];

#pragma unroll
    for (int s = 0; s < SPT; ++s) {
        int idx = base + s * BLOCK;
        float4 xv;
        if (!GUARD || idx < B) xv = ((const float4*)x)[idx];
        else xv = make_float4(0.f, 0.f, 0.f, 0.f);

        float c1, s1, c2, s2;
        __sincosf(xv.x, &s0[s], &c0[s]);
        __sincosf(xv.y, &s1, &c1);
        __sincosf(xv.z, &s2, &c2);
        __sincosf(xv.w, &s3[s], &c3[s]);

        G9[s][0] = 1.f;  G9[s][1] = c1;      G9[s][2] = s1;
        G9[s][3] = c2;   G9[s][4] = c1 * c2; G9[s][5] = s1 * c2;
        G9[s][6] = s2;   G9[s][7] = c1 * s2; G9[s][8] = s1 * s2;

        z[s][0] = z[s][1] = z[s][2] = z[s][3] = 0.f;
    }

    // t = t0 + 3*t1 + 9*t2 + 27*t3 ; combo = t1 + 3*t2 + 9*t3
#pragma unroll
    for (int t3 = 0; t3 < 3; ++t3) {
#pragma unroll
        for (int i9 = 0; i9 < 9; ++i9) {
            const int combo = i9 + 9 * t3;
            const float4 Ca = C[combo * 3 + 0];
            const float4 Cb = C[combo * 3 + 1];
            const float4 Cc = C[combo * 3 + 2];
#pragma unroll
            for (int s = 0; s < SPT; ++s) {
                float g = G9[s][i9];
                if (t3 == 1) g *= c3[s];
                if (t3 == 2) g *= s3[s];
                float r0 = fmaf(c0[s], Cb.x, fmaf(s0[s], Cc.x, Ca.x));
                float r1 = fmaf(c0[s], Cb.y, fmaf(s0[s], Cc.y, Ca.y));
                float r2 = fmaf(c0[s], Cb.z, fmaf(s0[s], Cc.z, Ca.z));
                float r3 = fmaf(c0[s], Cb.w, fmaf(s0[s], Cc.w, Ca.w));
                z[s][0] = fmaf(g, r0, z[s][0]);
                z[s][1] = fmaf(g, r1, z[s][1]);
                z[s][2] = fmaf(g, r2, z[s][2]);
                z[s][3] = fmaf(g, r3, z[s][3]);
            }
        }
    }

#pragma unroll
    for (int s = 0; s < SPT; ++s) {
        int idx = base + s * BLOCK;
        if (!GUARD || idx < B) {
            float4 o; o.x = z[s][0]; o.y = z[s][1]; o.z = z[s][2]; o.w = z[s][3];
            ((float4*)out)[idx] = o;
        }
    }
}

extern "C" void kernel_launch(void* const* d_in, const int* in_sizes, int n_in,
                              void* d_out, int out_size, void* d_ws, size_t ws_size,
                              hipStream_t stream) {
    const float* x = (const float*)d_in[0];
    const float* w = (const float*)d_in[1];
    float* out = (float*)d_out;

    int B = in_sizes[0] / 4;

    const int spb = BLOCK * SPT;
    if (B % spb == 0) {
        qlayer_kernel<false><<<B / spb, BLOCK, 0, stream>>>(x, w, out, B);
    } else {
        qlayer_kernel<true><<<(B + spb - 1) / spb, BLOCK, 0, stream>>>(x, w, out, B);
    }
}